// Round 1
// baseline (258.543 us; speedup 1.0000x reference)
//
#include <hip/hip_runtime.h>

// Problem: x (32,4,512,512) fp32.
// reference = InstanceNorm( sum_j w_j * ((x * k_j + 1) * 0.5) ), w_j = 2^j/15.
// Collapses to: c = x * K (single 3x3 depthwise, zero pad), then
// (c - mean_c) * rsqrt(var_c + 4e-5)   [eps scales by 1/0.25 since out = 0.5c+0.5]

#define H 512
#define W 512
#define PLANES 128              // 32 * 4
#define ROWBLKS 16              // 16 row-blocks of 32 rows per plane
#define ROWS_PER_TY 16          // each of 2 ty-groups does 16 rows

// combined kernel weights (x 1/30)
#define WT0 (-8.0f/30.0f)
#define WT1 (-4.0f/30.0f)
#define WT2 (-2.0f/30.0f)
#define WM  (-1.0f/30.0f)
// bottom row: -2/30, -4/30, -8/30 == WT2, WT1, WT0

__device__ __forceinline__ void load_row(const float* __restrict__ rowp, int c0, bool valid,
                                         float& l, float4& m, float& r) {
    if (valid) {
        m = *reinterpret_cast<const float4*>(rowp + c0);
        l = (c0 > 0)       ? rowp[c0 - 1] : 0.0f;
        r = (c0 + 4 < W)   ? rowp[c0 + 4] : 0.0f;
    } else {
        l = 0.0f; r = 0.0f; m = make_float4(0.0f, 0.0f, 0.0f, 0.0f);
    }
}

__device__ __forceinline__ float4 conv_row(float al, float4 a, float ar,
                                           float bl, float4 b, float br,
                                           float dl, float4 d, float dr) {
    float4 o;
    o.x = WT0*al  + WT1*a.x + WT2*a.y + WM*bl  + b.x + WM*b.y + WT2*dl  + WT1*d.x + WT0*d.y;
    o.y = WT0*a.x + WT1*a.y + WT2*a.z + WM*b.x + b.y + WM*b.z + WT2*d.x + WT1*d.y + WT0*d.z;
    o.z = WT0*a.y + WT1*a.z + WT2*a.w + WM*b.y + b.z + WM*b.w + WT2*d.y + WT1*d.z + WT0*d.w;
    o.w = WT0*a.z + WT1*a.w + WT2*ar  + WM*b.z + b.w + WM*br  + WT2*d.z + WT1*d.w + WT0*dr;
    return o;
}

// Pass 1: conv on the fly, accumulate per-plane sum & sumsq.
__global__ __launch_bounds__(256) void stats_kernel(const float* __restrict__ x,
                                                    float* __restrict__ ws) {
    const int plane  = blockIdx.x >> 4;   // / ROWBLKS
    const int rowblk = blockIdx.x & 15;
    const int tid = threadIdx.x;
    const int tx = tid & 127;             // column strip
    const int ty = tid >> 7;              // 0 or 1
    const int c0 = tx * 4;
    const int r0 = rowblk * 32 + ty * ROWS_PER_TY;

    const float* __restrict__ p = x + (size_t)plane * H * W;

    float al, ar, bl, br, dl, dr;
    float4 a4, b4, d4;
    load_row(p + (size_t)(r0 - 1) * W, c0, r0 > 0, al, a4, ar);
    load_row(p + (size_t)r0 * W,       c0, true,   bl, b4, br);

    float s = 0.0f, ss = 0.0f;
    for (int r = r0; r < r0 + ROWS_PER_TY; ++r) {
        load_row(p + (size_t)(r + 1) * W, c0, (r + 1) < H, dl, d4, dr);
        float4 o = conv_row(al, a4, ar, bl, b4, br, dl, d4, dr);
        s  += (o.x + o.y) + (o.z + o.w);
        ss += (o.x*o.x + o.y*o.y) + (o.z*o.z + o.w*o.w);
        al = bl; a4 = b4; ar = br;
        bl = dl; b4 = d4; br = dr;
    }

    // wave(64) reduction
    for (int off = 32; off > 0; off >>= 1) {
        s  += __shfl_down(s,  off);
        ss += __shfl_down(ss, off);
    }
    __shared__ float sh[8];
    const int wid = tid >> 6, lane = tid & 63;
    if (lane == 0) { sh[wid * 2] = s; sh[wid * 2 + 1] = ss; }
    __syncthreads();
    if (tid == 0) {
        float S  = (sh[0] + sh[2]) + (sh[4] + sh[6]);
        float SS = (sh[1] + sh[3]) + (sh[5] + sh[7]);
        atomicAdd(&ws[plane * 2 + 0], S);
        atomicAdd(&ws[plane * 2 + 1], SS);
    }
}

// Pass 2: recompute conv (x re-read hits Infinity Cache), normalize, write.
__global__ __launch_bounds__(256) void norm_kernel(const float* __restrict__ x,
                                                   const float* __restrict__ ws,
                                                   float* __restrict__ out) {
    const int plane  = blockIdx.x >> 4;
    const int rowblk = blockIdx.x & 15;
    const int tid = threadIdx.x;
    const int tx = tid & 127;
    const int ty = tid >> 7;
    const int c0 = tx * 4;
    const int r0 = rowblk * 32 + ty * ROWS_PER_TY;

    const float* __restrict__ p = x + (size_t)plane * H * W;
    float* __restrict__ q = out + (size_t)plane * H * W;

    const float invN = 1.0f / (float)(H * W);
    const float mean = ws[plane * 2 + 0] * invN;
    const float var  = ws[plane * 2 + 1] * invN - mean * mean;
    const float rstd = rsqrtf(var + 4e-5f);   // eps 1e-5 scaled by 1/0.25

    float al, ar, bl, br, dl, dr;
    float4 a4, b4, d4;
    load_row(p + (size_t)(r0 - 1) * W, c0, r0 > 0, al, a4, ar);
    load_row(p + (size_t)r0 * W,       c0, true,   bl, b4, br);

    for (int r = r0; r < r0 + ROWS_PER_TY; ++r) {
        load_row(p + (size_t)(r + 1) * W, c0, (r + 1) < H, dl, d4, dr);
        float4 o = conv_row(al, a4, ar, bl, b4, br, dl, d4, dr);
        float4 y;
        y.x = (o.x - mean) * rstd;
        y.y = (o.y - mean) * rstd;
        y.z = (o.z - mean) * rstd;
        y.w = (o.w - mean) * rstd;
        *reinterpret_cast<float4*>(q + (size_t)r * W + c0) = y;
        al = bl; a4 = b4; ar = br;
        bl = dl; b4 = d4; br = dr;
    }
}

extern "C" void kernel_launch(void* const* d_in, const int* in_sizes, int n_in,
                              void* d_out, int out_size, void* d_ws, size_t ws_size,
                              hipStream_t stream) {
    const float* x = (const float*)d_in[0];
    float* out = (float*)d_out;
    float* ws  = (float*)d_ws;

    // zero the per-plane (sum, sumsq) accumulators (ws is re-poisoned each call)
    hipMemsetAsync(ws, 0, PLANES * 2 * sizeof(float), stream);

    const dim3 grid(PLANES * ROWBLKS);   // 2048 blocks
    const dim3 block(256);
    stats_kernel<<<grid, block, 0, stream>>>(x, ws);
    norm_kernel <<<grid, block, 0, stream>>>(x, ws, out);
}

// Round 4
// 251.461 us; speedup vs baseline: 1.0282x; 1.0282x over previous
//
#include <hip/hip_runtime.h>

// Problem: x (32,4,512,512) fp32.
// reference = InstanceNorm( sum_j (2^j/15) * ((x * k_j + 1) * 0.5) )
// Collapses to: c = x * K (single 3x3 depthwise, zero pad, K entries sum to 0,
// center weight 1), then (c - mean_c) * rsqrt(var_c + 4e-5)
// [affine 0.5c+0.5 cancels in InstanceNorm; eps 1e-5 scales by 1/0.25]
//
// Layout: 2048 blocks (16 per plane), 256 thr = 4 waves. Each wave owns an
// independent 16-row x 256-col strip: 64 lanes x float4. Halo columns come
// from neighbor lanes via shfl; only lanes 0/63 do a scalar halo load
// -> 3 VMEM insts per row per wave (vs 192 in the per-thread-halo version).

#define H 512
#define W 512
#define PLANES 128
#define NBLOCKS (PLANES * 16)

typedef float vfloat4 __attribute__((ext_vector_type(4)));

// combined kernel weights (x 1/30): [-8 -4 -2; -1 30 -1; -2 -4 -8]
#define WT0 (-8.0f/30.0f)
#define WT1 (-4.0f/30.0f)
#define WT2 (-2.0f/30.0f)
#define WM  (-1.0f/30.0f)

// Load one row segment for a wave: float4 per lane + shfl halos.
// `valid` is wave-uniform (row in bounds). ch = segment start col (0 or 256).
__device__ __forceinline__ void wload(const float* __restrict__ rowp, int c0, int ch,
                                      int lane, bool valid,
                                      float& l, float4& m, float& r) {
    float lval = 0.0f, rval = 0.0f;
    if (valid) {
        m = *reinterpret_cast<const float4*>(rowp + c0);
        if (lane == 0  && ch > 0)        lval = rowp[ch - 1];
        if (lane == 63 && ch + 256 < W)  rval = rowp[ch + 256];
    } else {
        m = make_float4(0.0f, 0.0f, 0.0f, 0.0f);
    }
    float fromL = __shfl_up(m.w, 1);    // lane i <- lane i-1 last elem
    float fromR = __shfl_down(m.x, 1);  // lane i <- lane i+1 first elem
    l = (lane == 0)  ? lval : fromL;
    r = (lane == 63) ? rval : fromR;
}

// 180-degree-symmetric kernel -> pair taps: 4 FMA + 4 ADD per output.
__device__ __forceinline__ float4 conv_row(float al, float4 a, float ar,
                                           float bl, float4 b, float br,
                                           float dl, float4 d, float dr) {
    float4 o;
    o.x = b.x + WT0*(al  + d.y) + WT1*(a.x + d.x) + WT2*(a.y + dl ) + WM*(bl  + b.y);
    o.y = b.y + WT0*(a.x + d.z) + WT1*(a.y + d.y) + WT2*(a.z + d.x) + WM*(b.x + b.z);
    o.z = b.z + WT0*(a.y + d.w) + WT1*(a.z + d.z) + WT2*(a.w + d.y) + WM*(b.y + b.w);
    o.w = b.w + WT0*(a.z + dr ) + WT1*(a.w + d.w) + WT2*(ar  + d.z) + WM*(b.z + br );
    return o;
}

// Pass 1: conv on the fly, per-block (sum, sumsq) partial via plain stores.
__global__ __launch_bounds__(256) void stats_kernel(const float* __restrict__ x,
                                                    float* __restrict__ ws) {
    const int plane = blockIdx.x >> 4;
    const int slab  = blockIdx.x & 15;          // 32-row slab
    const int tid  = threadIdx.x;
    const int wid  = tid >> 6;
    const int lane = tid & 63;
    const int ch = (wid & 1) * 256;             // col segment start
    const int c0 = ch + lane * 4;
    const int r0 = slab * 32 + (wid >> 1) * 16; // 16-row strip

    const float* __restrict__ p = x + (size_t)plane * H * W;

    float al, ar, bl, br, dl, dr;
    float4 a4, b4, d4;
    wload(p + (size_t)(r0 - 1) * W, c0, ch, lane, r0 > 0, al, a4, ar);
    wload(p + (size_t)r0 * W,       c0, ch, lane, true,   bl, b4, br);

    float s = 0.0f, ss = 0.0f;
    for (int r = r0; r < r0 + 16; ++r) {
        wload(p + (size_t)(r + 1) * W, c0, ch, lane, (r + 1) < H, dl, d4, dr);
        float4 o = conv_row(al, a4, ar, bl, b4, br, dl, d4, dr);
        s  += (o.x + o.y) + (o.z + o.w);
        ss += (o.x*o.x + o.y*o.y) + (o.z*o.z + o.w*o.w);
        al = bl; a4 = b4; ar = br;
        bl = dl; b4 = d4; br = dr;
    }

    for (int off = 32; off > 0; off >>= 1) {
        s  += __shfl_down(s,  off);
        ss += __shfl_down(ss, off);
    }
    __shared__ float sh[8];
    if (lane == 0) { sh[wid * 2] = s; sh[wid * 2 + 1] = ss; }
    __syncthreads();
    if (tid == 0) {
        ws[blockIdx.x * 2 + 0] = (sh[0] + sh[2]) + (sh[4] + sh[6]);
        ws[blockIdx.x * 2 + 1] = (sh[1] + sh[3]) + (sh[5] + sh[7]);
    }
}

// Pass 2: reduce the plane's 16 partials, recompute conv (x is L3-resident),
// normalize, nontemporal-store (keep x resident in L3, out is never re-read).
__global__ __launch_bounds__(256) void norm_kernel(const float* __restrict__ x,
                                                   const float* __restrict__ ws,
                                                   float* __restrict__ out) {
    const int plane = blockIdx.x >> 4;
    const int slab  = blockIdx.x & 15;
    const int tid  = threadIdx.x;
    const int wid  = tid >> 6;
    const int lane = tid & 63;
    const int ch = (wid & 1) * 256;
    const int c0 = ch + lane * 4;
    const int r0 = slab * 32 + (wid >> 1) * 16;

    // plane stats: 16 (s,ss) pairs; wave 0 reduces, LDS-broadcasts.
    __shared__ float sb[2];
    if (tid < 64) {
        float s = 0.0f, ss = 0.0f;
        if (lane < 16) {
            s  = ws[plane * 32 + lane * 2 + 0];
            ss = ws[plane * 32 + lane * 2 + 1];
        }
        for (int off = 8; off > 0; off >>= 1) {
            s  += __shfl_down(s,  off);
            ss += __shfl_down(ss, off);
        }
        if (lane == 0) { sb[0] = s; sb[1] = ss; }
    }
    __syncthreads();
    const float invN = 1.0f / (float)(H * W);
    const float mean = sb[0] * invN;
    const float var  = sb[1] * invN - mean * mean;
    const float rstd = rsqrtf(var + 4e-5f);

    const float* __restrict__ p = x + (size_t)plane * H * W;
    float* __restrict__ q = out + (size_t)plane * H * W;

    float al, ar, bl, br, dl, dr;
    float4 a4, b4, d4;
    wload(p + (size_t)(r0 - 1) * W, c0, ch, lane, r0 > 0, al, a4, ar);
    wload(p + (size_t)r0 * W,       c0, ch, lane, true,   bl, b4, br);

    for (int r = r0; r < r0 + 16; ++r) {
        wload(p + (size_t)(r + 1) * W, c0, ch, lane, (r + 1) < H, dl, d4, dr);
        float4 o = conv_row(al, a4, ar, bl, b4, br, dl, d4, dr);
        vfloat4 y;
        y.x = (o.x - mean) * rstd;
        y.y = (o.y - mean) * rstd;
        y.z = (o.z - mean) * rstd;
        y.w = (o.w - mean) * rstd;
        __builtin_nontemporal_store(y, reinterpret_cast<vfloat4*>(q + (size_t)r * W + c0));
        al = bl; a4 = b4; ar = br;
        bl = dl; b4 = d4; br = dr;
    }
}

extern "C" void kernel_launch(void* const* d_in, const int* in_sizes, int n_in,
                              void* d_out, int out_size, void* d_ws, size_t ws_size,
                              hipStream_t stream) {
    const float* x = (const float*)d_in[0];
    float* out = (float*)d_out;
    float* ws  = (float*)d_ws;

    stats_kernel<<<dim3(NBLOCKS), dim3(256), 0, stream>>>(x, ws);
    norm_kernel <<<dim3(NBLOCKS), dim3(256), 0, stream>>>(x, ws, out);
}